// Round 10
// baseline (412.082 us; speedup 1.0000x reference)
//
#include <hip/hip_runtime.h>
#include <stdint.h>

typedef unsigned short u16;
typedef __attribute__((ext_vector_type(8))) short bf16x8;      // 8 bf16 = 4 VGPRs
typedef __attribute__((ext_vector_type(8))) unsigned short u16x8;
typedef __attribute__((ext_vector_type(4))) float f32x4;

#define B_  2
#define T_  4096
#define C_  2048
#define NH  16
#define NKV 4
#define HD  128

__device__ __forceinline__ u16 f2bf(float f) {
  union { float f; uint32_t u; } v; v.f = f;
  uint32_t u = v.u;
  u += 0x7fffu + ((u >> 16) & 1u);   // RNE
  return (u16)(u >> 16);
}
__device__ __forceinline__ float bf2f(u16 h) {
  union { uint32_t u; float f; } v; v.u = ((uint32_t)h) << 16;
  return v.f;
}

__device__ __forceinline__ void gload_lds16(const u16* g, u16* l) {
  __builtin_amdgcn_global_load_lds(
      (const __attribute__((address_space(1))) void*)g,
      (__attribute__((address_space(3))) void*)l, 16, 0, 0);
}

// ---------------- fused f32 -> bf16 convert (x, wq, wk, wv, wo in one grid) ----------------
__global__ void cvt_all(const float* __restrict__ x, const float* __restrict__ wq,
                        const float* __restrict__ wk, const float* __restrict__ wv,
                        const float* __restrict__ wo, u16* __restrict__ xb,
                        u16* __restrict__ wqkv, u16* __restrict__ wob) {
  long i = ((long)blockIdx.x * 256 + threadIdx.x) * 4;
  const float* src; u16* dst; long off;
  if (i < 16777216L)      { src = x;  dst = xb;              off = i; }
  else if (i < 20971520L) { src = wq; dst = wqkv;            off = i - 16777216L; }
  else if (i < 22020096L) { src = wk; dst = wqkv + 4194304L; off = i - 20971520L; }
  else if (i < 23068672L) { src = wv; dst = wqkv + 5242880L; off = i - 22020096L; }
  else                    { src = wo; dst = wob;             off = i - 23068672L; }
  float4 v = *(const float4*)(src + off);
  ushort4 o4;
  o4.x = f2bf(v.x); o4.y = f2bf(v.y); o4.z = f2bf(v.z); o4.w = f2bf(v.w);
  *(ushort4*)(dst + off) = o4;
}

// ---------------- standalone RoPE on qkv [B*T][3072]; Q pre-scaled (R0-proven) ----------------
__global__ void rope_kernel(u16* __restrict__ qkv, const float* __restrict__ cache) {
  const int PH = (NH + NKV) * (HD / 2);   // 1280 pairs per row
  long idx = (long)blockIdx.x * blockDim.x + threadIdx.x;
  if (idx >= (long)B_ * T_ * PH) return;
  int row = (int)(idx / PH);
  int rem = (int)(idx % PH);
  int hh = rem >> 6;
  int i  = rem & 63;
  int t  = row & (T_ - 1);
  float sc = (hh < NH) ? 0.1275174315f : 1.0f;   // q heads: fold scale*log2(e)
  float c = cache[t * 128 + 2 * i] * sc;
  float s = cache[t * 128 + 2 * i + 1] * sc;
  u16* p = qkv + (long)row * 3072 + hh * HD + 2 * i;
  float x0 = bf2f(p[0]), x1 = bf2f(p[1]);
  p[0] = f2bf(x0 * c - x1 * s);
  p[1] = f2bf(x0 * s + x1 * c);
}

// ---------------- K rearrange: frag-linear layout ----------------
// K2[bk][kb=key/16][ks=d/32][q4][l16=key%16][e=d%8]
__global__ void krearr(const u16* __restrict__ qkv, u16* __restrict__ K2) {
  int gid = blockIdx.x * 256 + threadIdx.x;
  int r = gid & 65535, bk = gid >> 16;
  int l16 = r & 15, q4 = (r >> 4) & 3, ks = (r >> 6) & 3, kb = r >> 8;
  int bb = bk >> 2, kv = bk & 3;
  const u16* src = qkv + ((long)(bb * T_ + kb * 16 + l16)) * 3072 + 2048 + kv * HD +
                   ks * 32 + q4 * 8;
  *(u16x8*)(K2 + (long)bk * 524288 + (long)r * 8) = *(const u16x8*)src;
}

// ---------------- V rearrange via LDS transpose (coalesced both sides) ----------------
// V2[bk][kc=key/128][jd=d/16][ks=(key%128)/32][q4][l16=d%16][e=key%8]
__global__ __launch_bounds__(256) void vrearr2(const u16* __restrict__ qkv,
                                               u16* __restrict__ V2) {
  const int bid = blockIdx.x;          // 0..255
  const int bk = bid >> 5, kc = bid & 31;
  const int bb = bk >> 2, kv = bk & 3;
  const int t = threadIdx.x;
  __shared__ u16 L[128 * 136];         // [key][d], pad 8 u16 (16B-aligned rows)
  {
    int key = t >> 1;
    int dh = (t & 1) * 64;
    const u16* src = qkv + ((long)(bb * T_ + kc * 128 + key)) * 3072 + 2560 + kv * HD + dh;
    u16* dst = L + key * 136 + dh;
#pragma unroll
    for (int u = 0; u < 8; u++)
      *(u16x8*)(dst + u * 8) = *(const u16x8*)(src + u * 8);
  }
  __syncthreads();
  u16* out = V2 + (long)bk * 524288 + (long)kc * 16384;
#pragma unroll
  for (int step = 0; step < 8; step++) {
    int o = step * 256 + t;            // 0..2047
    int l16 = o & 15, q4 = (o >> 4) & 3, ks = (o >> 6) & 3, jd = (o >> 8) & 7;
    int keyb = ks * 32 + q4 * 8;
    int d = jd * 16 + l16;
    u16x8 v;
#pragma unroll
    for (int e = 0; e < 8; e++) v[e] = L[(keyb + e) * 136 + d];
    *(u16x8*)(out + (long)o * 8) = v;
  }
}

// ---------------- bf16 GEMM: C[M][N] = A[M][K] * B[N][K]^T ----------------
// 256x256 tile, BK=64, 8 waves (2M x 4N), double-buffered 128 KiB LDS.
// READ-AHEAD pipeline, 2 barriers per K-tile (R2 structure, proven 121.6 us).
// R10: rope fusion REMOVED (ledger: plain 121.6 vs fused-R8 142.6 vs fused-R9
// 178.3 vs standalone rope 16.5 -> standalone wins; epilogue LDS round-trip
// costs more than a memory-bound pass).
#define GBAR() __builtin_amdgcn_s_barrier()
#define LGKM0() do { asm volatile("s_waitcnt lgkmcnt(0)" ::: "memory"); \
                     __builtin_amdgcn_sched_barrier(0); } while (0)

template <int WRITE_BF16>
__global__ __launch_bounds__(512, 2) void gemm256(const u16* __restrict__ A,
                                                  const u16* __restrict__ Bw,
                                                  void* __restrict__ Cv,
                                                  int M, int N, int K) {
  __shared__ __align__(16) u16 lds[65536];   // 128 KiB
  const int tid = threadIdx.x;
  const int lane = tid & 63;
  const int wave = tid >> 6;
  const int q4 = lane >> 4, l16 = lane & 15;
  const int wm = wave >> 2, wn = wave & 3;

  // bijective XCD swizzle (launcher guarantees nwg % 8 == 0)
  const int nwg = gridDim.x * gridDim.y;
  const int orig = blockIdx.y * gridDim.x + blockIdx.x;
  const int swz = (orig & 7) * (nwg >> 3) + (orig >> 3);
  const int bm = swz / gridDim.x, bn = swz % gridDim.x;
  const long m0 = (long)bm * 256, n0 = (long)bn * 256;

  // ---- staging addressing: thread t -> LDS linear t*16 bytes (+8192) ----
  const int srow = tid >> 2;            // 0..127  (second load: +128)
  const int slot = tid & 3;
  const int sx = (slot ^ ((srow >> 1) & 3)) * 8;   // (srow+128) gives same XOR
  const u16* Ag0 = A + (m0 + srow) * K + sx;
  const u16* Ag1 = A + (m0 + srow + 128) * K + sx;
  const u16* Bg0 = Bw + (n0 + srow) * K + sx;
  const u16* Bg1 = Bw + (n0 + srow + 128) * K + sx;
  u16* ldst = lds + tid * 8;            // u16 units

  const int nkt = K >> 6;

#define STAGE_A(bufi, kh, kt)                                  \
  do {                                                         \
    long ko = ((long)(kt) << 6) + ((kh) << 5);                 \
    u16* d = ldst + (bufi) * 32768 + (kh) * 8192;              \
    gload_lds16(Ag0 + ko, d);                                  \
    gload_lds16(Ag1 + ko, d + 4096);                           \
  } while (0)
#define STAGE_B(bufi, kh, kt)                                  \
  do {                                                         \
    long ko = ((long)(kt) << 6) + ((kh) << 5);                 \
    u16* d = ldst + (bufi) * 32768 + 16384 + (kh) * 8192;      \
    gload_lds16(Bg0 + ko, d);                                  \
    gload_lds16(Bg1 + ko, d + 4096);                           \
  } while (0)

  // fragment LDS offsets (u16 units) for kh=0; kh=1 adds 8192.
  int offA[8], offB[4];
#pragma unroll
  for (int m = 0; m < 8; m++) {
    int r = wm * 128 + m * 16 + l16;
    offA[m] = r * 32 + ((q4 ^ ((r >> 1) & 3)) << 3);
  }
#pragma unroll
  for (int n = 0; n < 4; n++) {
    int r = wn * 64 + n * 16 + l16;
    offB[n] = 16384 + r * 32 + ((q4 ^ ((r >> 1) & 3)) << 3);
  }

  f32x4 acc[8][4] = {};

  // ---- prologue: tile0 (4 half-stages) + tile1 k0 (2 half-stages) ----
  STAGE_A(0, 0, 0); STAGE_B(0, 0, 0); STAGE_A(0, 1, 0); STAGE_B(0, 1, 0);
  if (nkt > 1) {
    STAGE_A(1, 0, 1); STAGE_B(1, 0, 1);
    asm volatile("s_waitcnt vmcnt(4)" ::: "memory");
  } else {
    asm volatile("s_waitcnt vmcnt(0)" ::: "memory");
  }
  GBAR();

  bf16x8 afX[4], afY[4], bvA[4], bvB[4];
  for (int kt = 0; kt < nkt; kt++) {
    const int bo = (kt & 1) * 32768;    // current read buffer offset (u16)
    // ---- P1: R1 (cold) ; stage A-k1 ; wait ; R2 under MFMA ----
#pragma unroll
    for (int m = 0; m < 4; m++) afX[m] = *(const bf16x8*)(lds + bo + offA[m]);
#pragma unroll
    for (int n = 0; n < 4; n++) bvA[n] = *(const bf16x8*)(lds + bo + offB[n]);
    if (kt + 1 < nkt) STAGE_A((kt + 1) & 1, 1, kt + 1);
    LGKM0();
#pragma unroll
    for (int m = 0; m < 4; m++) afY[m] = *(const bf16x8*)(lds + bo + offA[4 + m]);
    __builtin_amdgcn_s_setprio(1);
#pragma unroll
    for (int m = 0; m < 4; m++)
#pragma unroll
      for (int n = 0; n < 4; n++)
        acc[m][n] = __builtin_amdgcn_mfma_f32_16x16x32_bf16(afX[m], bvA[n], acc[m][n], 0, 0, 0);
    __builtin_amdgcn_s_setprio(0);
    // ---- P2: stage B-k1 ; wait R2 ; R3 under MFMA ; mid-BAR ----
    if (kt + 1 < nkt) STAGE_B((kt + 1) & 1, 1, kt + 1);
    LGKM0();
#pragma unroll
    for (int m = 0; m < 4; m++) afX[m] = *(const bf16x8*)(lds + bo + 8192 + offA[m]);
#pragma unroll
    for (int n = 0; n < 4; n++) bvB[n] = *(const bf16x8*)(lds + bo + 8192 + offB[n]);
    __builtin_amdgcn_s_setprio(1);
#pragma unroll
    for (int m = 0; m < 4; m++)
#pragma unroll
      for (int n = 0; n < 4; n++)
        acc[4 + m][n] = __builtin_amdgcn_mfma_f32_16x16x32_bf16(afY[m], bvA[n], acc[4 + m][n], 0, 0, 0);
    __builtin_amdgcn_s_setprio(0);
    GBAR();                              // k0 globally consumed -> reusable
    // ---- P3: stage A-k0(kt+2) into cur ; wait R3 ; R4 under MFMA ----
    if (kt + 2 < nkt) STAGE_A(kt & 1, 0, kt + 2);
    LGKM0();
#pragma unroll
    for (int m = 0; m < 4; m++) afY[m] = *(const bf16x8*)(lds + bo + 8192 + offA[4 + m]);
    __builtin_amdgcn_s_setprio(1);
#pragma unroll
    for (int m = 0; m < 4; m++)
#pragma unroll
      for (int n = 0; n < 4; n++)
        acc[m][n] = __builtin_amdgcn_mfma_f32_16x16x32_bf16(afX[m], bvB[n], acc[m][n], 0, 0, 0);
    __builtin_amdgcn_s_setprio(0);
    // ---- P4: stage B-k0(kt+2) ; wait R4 ; MFMA ; counted vmcnt ; BAR ----
    if (kt + 2 < nkt) STAGE_B(kt & 1, 0, kt + 2);
    LGKM0();
    __builtin_amdgcn_s_setprio(1);
#pragma unroll
    for (int m = 0; m < 4; m++)
#pragma unroll
      for (int n = 0; n < 4; n++)
        acc[4 + m][n] = __builtin_amdgcn_mfma_f32_16x16x32_bf16(afY[m], bvB[n], acc[4 + m][n], 0, 0, 0);
    __builtin_amdgcn_s_setprio(0);
    if (kt + 2 < nkt)
      asm volatile("s_waitcnt vmcnt(4)" ::: "memory");
    else
      asm volatile("s_waitcnt vmcnt(0)" ::: "memory");
    GBAR();
  }
#undef STAGE_A
#undef STAGE_B

  // ---- epilogue: C write (C/D frag: row=q4*4+r, col=l16) ----
  const long crow0 = m0 + wm * 128;
  const long ccol0 = n0 + wn * 64;
#pragma unroll
  for (int m = 0; m < 8; m++)
#pragma unroll
    for (int n = 0; n < 4; n++)
#pragma unroll
      for (int r = 0; r < 4; r++) {
        long row = crow0 + m * 16 + q4 * 4 + r;
        if (WRITE_BF16)
          ((u16*)Cv)[row * (long)N + ccol0 + n * 16 + l16] = f2bf(acc[m][n][r]);
        else
          ((float*)Cv)[row * (long)N + ccol0 + n * 16 + l16] = acc[m][n][r];
      }
}

// ---------------- sliding-window attention (R9 structure, kept: it measured -17.6 us) ----
//  * 256-row q-tile, 512 threads / 8 waves -> 512 blocks, 1 block/CU (132 KB).
//  * K and V staged in LDS via async global_load_lds; counted vmcnt(4) twice
//    per chunk (no cold drains, no per-j global-latency exposure).
//  * Band-liveness skip at 32-key granularity, identical sets for QK and PV.
//  * XCD swizzle: 64 blocks/XCD = one (b,kvh) -> 2 MB K2/V2 L2-pinned.
__global__ __launch_bounds__(512, 2) void attn_kernel(const u16* __restrict__ qkv,
                                                      const u16* __restrict__ K2,
                                                      const u16* __restrict__ V2,
                                                      u16* __restrict__ y) {
  const int lin = blockIdx.x + (int)gridDim.x * (blockIdx.y + (int)gridDim.y * blockIdx.z);
  const int swz = (lin & 7) * 64 + (lin >> 3);   // bijective: 512 = 8*64
  const int tc = swz & 15, h = (swz >> 4) & 15, b = swz >> 8;
  const int t0 = tc * 256;
  const int kvh = h >> 2;
  __shared__ __align__(16) u16 Kl[16384];        // 32 KB staged K chunk
  __shared__ __align__(16) u16 Vl[16384];        // 32 KB staged V chunk
  __shared__ u16 Pl[8 * 32 * 136];               // 69.6 KB wave-private P
  const int tid = threadIdx.x, wave = tid >> 6, lane = tid & 63;
  const int q4 = lane >> 4, l16 = lane & 15;
  u16* Pw = Pl + wave * (32 * 136);
  const int wq0 = t0 + 32 * wave;                // wave's first q row

  bf16x8 qf[2][4];
#pragma unroll
  for (int i = 0; i < 2; i++)
#pragma unroll
    for (int ks = 0; ks < 4; ks++)
      qf[i][ks] = *(const bf16x8*)(qkv +
          ((long)(b * T_ + wq0 + 16 * i + l16)) * 3072 + h * HD + ks * 32 + q4 * 8);

  f32x4 O[2][8] = {};
  float l_i[2][4] = {};

  const u16* KB = K2 + (long)(b * NKV + kvh) * 524288;
  const u16* VB = V2 + (long)(b * NKV + kvh) * 524288;

  int kstart = t0 - 256; if (kstart < 0) kstart = 0;
  const int kend = t0 + 128;                     // rows t0..t0+255 need keys to t0+255

  // prologue: issue K(kstart)
  {
    const u16* Kg = KB + ((long)(kstart >> 4)) * 2048;
#pragma unroll
    for (int i = 0; i < 4; i++)
      gload_lds16(Kg + i * 4096 + tid * 8, Kl + i * 4096 + tid * 8);
  }

  for (int k0 = kstart; k0 <= kend; k0 += 128) {
    // 1. issue V(k0)  (Vl free: prev PV reads fenced by trailing barrier)
    {
      const u16* Vg = VB + ((long)(k0 >> 7)) * 16384;
#pragma unroll
      for (int i = 0; i < 4; i++)
        gload_lds16(Vg + i * 4096 + tid * 8, Vl + i * 4096 + tid * 8);
    }
    // 2-3. wait K(k0) (4 newest = V), make visible
    asm volatile("s_waitcnt vmcnt(4)" ::: "memory");
    GBAR();
    // 4. QK for live 32-key chunks; P -> wave-private LDS
    const int dbase0 = wq0 + q4 * 4 - k0 - l16;
#pragma unroll
    for (int kc = 0; kc < 4; kc++) {
      const bool live = (k0 + 32 * kc <= wq0 + 31) && (k0 + 32 * kc + 31 >= wq0 - 255);
      if (!live) continue;
#pragma unroll
      for (int jh = 0; jh < 2; jh++) {
        const int j = kc * 2 + jh;
        bf16x8 kf[4];
#pragma unroll
        for (int ks = 0; ks < 4; ks++)
          kf[ks] = *(const bf16x8*)(Kl + j * 2048 + ks * 512 + lane * 8);
        f32x4 s0 = {}, s1 = {};
#pragma unroll
        for (int ks = 0; ks < 4; ks++) {
          s0 = __builtin_amdgcn_mfma_f32_16x16x32_bf16(qf[0][ks], kf[ks], s0, 0, 0, 0);
          s1 = __builtin_amdgcn_mfma_f32_16x16x32_bf16(qf[1][ks], kf[ks], s1, 0, 0, 0);
        }
#pragma unroll
        for (int r = 0; r < 4; r++) {
          int d0 = dbase0 + r - 16 * j;               // q - k for i=0
          float p0 = __builtin_amdgcn_exp2f(s0[r]);
          p0 = ((unsigned)d0 <= 255u) ? p0 : 0.f;     // band mask
          l_i[0][r] += p0;
          Pw[(q4 * 4 + r) * 136 + 16 * j + l16] = f2bf(p0);
          int d1 = d0 + 16;                            // i=1
          float p1 = __builtin_amdgcn_exp2f(s1[r]);
          p1 = ((unsigned)d1 <= 255u) ? p1 : 0.f;
          l_i[1][r] += p1;
          Pw[(16 + q4 * 4 + r) * 136 + 16 * j + l16] = f2bf(p1);
        }
      }
    }
    // 5. all waves done reading Kl -> safe to restage
    GBAR();
    // 6-7. issue K(next); wait V (4 newest = next-K)
    if (k0 + 128 <= kend) {
      const u16* Kg = KB + ((long)((k0 + 128) >> 4)) * 2048;
#pragma unroll
      for (int i = 0; i < 4; i++)
        gload_lds16(Kg + i * 4096 + tid * 8, Kl + i * 4096 + tid * 8);
      asm volatile("s_waitcnt vmcnt(4)" ::: "memory");
    } else {
      asm volatile("s_waitcnt vmcnt(0)" ::: "memory");
    }
    // 8. V visible
    GBAR();
    // 9. PV for live chunks (same liveness as QK -> P fully defined)
#pragma unroll
    for (int ks = 0; ks < 4; ks++) {
      const bool live = (k0 + 32 * ks <= wq0 + 31) && (k0 + 32 * ks + 31 >= wq0 - 255);
      if (!live) continue;
      bf16x8 pf0 = *(const bf16x8*)(&Pw[l16 * 136 + ks * 32 + q4 * 8]);
      bf16x8 pf1 = *(const bf16x8*)(&Pw[(16 + l16) * 136 + ks * 32 + q4 * 8]);
#pragma unroll
      for (int jd = 0; jd < 8; jd++) {
        bf16x8 vf = *(const bf16x8*)(Vl + (jd * 4 + ks) * 512 + lane * 8);
        O[0][jd] = __builtin_amdgcn_mfma_f32_16x16x32_bf16(pf0, vf, O[0][jd], 0, 0, 0);
        O[1][jd] = __builtin_amdgcn_mfma_f32_16x16x32_bf16(pf1, vf, O[1][jd], 0, 0, 0);
      }
    }
    // 10. all waves done reading Vl -> next V-issue safe
    GBAR();
  }
  // ---- finalize: reduce l across the 16-lane row groups, divide, store ----
#pragma unroll
  for (int d = 1; d < 16; d <<= 1)
#pragma unroll
    for (int i = 0; i < 2; i++)
#pragma unroll
      for (int r = 0; r < 4; r++)
        l_i[i][r] += __shfl_xor(l_i[i][r], d, 64);
#pragma unroll
  for (int i = 0; i < 2; i++)
#pragma unroll
    for (int r = 0; r < 4; r++) {
      float inv = 1.0f / l_i[i][r];
      long row = (long)(b * T_ + wq0 + 16 * i + q4 * 4 + r);
#pragma unroll
      for (int jd = 0; jd < 8; jd++)
        y[row * 2048 + h * HD + 16 * jd + l16] = f2bf(O[i][jd][r] * inv);
    }
}

// ---------------- launcher ----------------
extern "C" void kernel_launch(void* const* d_in, const int* in_sizes, int n_in,
                              void* d_out, int out_size, void* d_ws, size_t ws_size,
                              hipStream_t stream) {
  const float* x    = (const float*)d_in[0];
  const float* wq   = (const float*)d_in[1];
  const float* wk   = (const float*)d_in[2];
  const float* wv   = (const float*)d_in[3];
  const float* wo   = (const float*)d_in[4];
  const float* rope = (const float*)d_in[5];
  float* out = (float*)d_out;

  u16* xb   = (u16*)d_ws;                       // 8192*2048
  u16* wqkv = xb + (long)8192 * 2048;           // 3072*2048
  u16* wob  = wqkv + (long)3072 * 2048;         // 2048*2048
  u16* qkv  = wob + (long)2048 * 2048;          // 8192*3072
  u16* V2   = qkv + (long)8192 * 3072;          // 4.19M el
  u16* K2   = wqkv;                             // alias: wqkv dead after gemm1
  u16* yb   = xb;                               // reuse

  // one fused convert pass: 27262976 elements = 26624 blocks * 1024 el
  cvt_all<<<dim3(26624), dim3(256), 0, stream>>>(x, wq, wk, wv, wo, xb, wqkv, wob);

  // GEMM1 (plain): qkv = x @ wqkv^T
  gemm256<1><<<dim3(3072 / 256, 8192 / 256), dim3(512), 0, stream>>>(
      xb, wqkv, (void*)qkv, 8192, 3072, 2048);

  // standalone RoPE (R0-proven; ledger beats fused variants)
  long npairs = (long)B_ * T_ * (NH + NKV) * (HD / 2);
  rope_kernel<<<dim3((unsigned)((npairs + 255) / 256)), dim3(256), 0, stream>>>(qkv, rope);

  krearr<<<dim3(2048), dim3(256), 0, stream>>>(qkv, K2);
  vrearr2<<<dim3(256), dim3(256), 0, stream>>>(qkv, V2);

  attn_kernel<<<dim3(T_ / 256, NH, B_), dim3(512), 0, stream>>>(qkv, K2, V2, yb);

  gemm256<0><<<dim3(2048 / 256, 8192 / 256), dim3(512), 0, stream>>>(
      yb, wob, (void*)out, 8192, 2048, 2048);
}

// Round 11
// 395.818 us; speedup vs baseline: 1.0411x; 1.0411x over previous
//
#include <hip/hip_runtime.h>
#include <stdint.h>

typedef unsigned short u16;
typedef __attribute__((ext_vector_type(8))) short bf16x8;      // 8 bf16 = 4 VGPRs
typedef __attribute__((ext_vector_type(8))) unsigned short u16x8;
typedef __attribute__((ext_vector_type(4))) float f32x4;

#define B_  2
#define T_  4096
#define C_  2048
#define NH  16
#define NKV 4
#define HD  128

__device__ __forceinline__ u16 f2bf(float f) {
  union { float f; uint32_t u; } v; v.f = f;
  uint32_t u = v.u;
  u += 0x7fffu + ((u >> 16) & 1u);   // RNE
  return (u16)(u >> 16);
}
__device__ __forceinline__ float bf2f(u16 h) {
  union { uint32_t u; float f; } v; v.u = ((uint32_t)h) << 16;
  return v.f;
}

__device__ __forceinline__ void gload_lds16(const u16* g, u16* l) {
  __builtin_amdgcn_global_load_lds(
      (const __attribute__((address_space(1))) void*)g,
      (__attribute__((address_space(3))) void*)l, 16, 0, 0);
}

// ---------------- fused f32 -> bf16 convert (x, wq, wk, wv, wo in one grid) ----------------
__global__ void cvt_all(const float* __restrict__ x, const float* __restrict__ wq,
                        const float* __restrict__ wk, const float* __restrict__ wv,
                        const float* __restrict__ wo, u16* __restrict__ xb,
                        u16* __restrict__ wqkv, u16* __restrict__ wob) {
  long i = ((long)blockIdx.x * 256 + threadIdx.x) * 4;
  const float* src; u16* dst; long off;
  if (i < 16777216L)      { src = x;  dst = xb;              off = i; }
  else if (i < 20971520L) { src = wq; dst = wqkv;            off = i - 16777216L; }
  else if (i < 22020096L) { src = wk; dst = wqkv + 4194304L; off = i - 20971520L; }
  else if (i < 23068672L) { src = wv; dst = wqkv + 5242880L; off = i - 22020096L; }
  else                    { src = wo; dst = wob;             off = i - 23068672L; }
  float4 v = *(const float4*)(src + off);
  ushort4 o4;
  o4.x = f2bf(v.x); o4.y = f2bf(v.y); o4.z = f2bf(v.z); o4.w = f2bf(v.w);
  *(ushort4*)(dst + off) = o4;
}

// ---------------- K rearrange + fused K-RoPE ----------------
// K2[bk][kb=key/16][ks=d/32][q4][l16=key%16][e=d%8]
// R11: rope applied here (K read exactly once; pair (2i,2i+1) = adjacent e in
// the same u16x8 -> in-register rotation, 32 B L2-cached cos/sin per thread).
// Replaces the standalone rope pass (measured ~78 us by budget closure).
__global__ void krearr(const u16* __restrict__ qkv, u16* __restrict__ K2,
                       const float* __restrict__ cache) {
  int gid = blockIdx.x * 256 + threadIdx.x;
  int r = gid & 65535, bk = gid >> 16;
  int l16 = r & 15, q4 = (r >> 4) & 3, ks = (r >> 6) & 3, kb = r >> 8;
  int bb = bk >> 2, kv = bk & 3;
  int t = kb * 16 + l16;
  int dd = ks * 32 + q4 * 8;
  const u16* src = qkv + ((long)(bb * T_ + t)) * 3072 + 2048 + kv * HD + dd;
  u16x8 v = *(const u16x8*)src;
  float4 ca = *(const float4*)(cache + t * 128 + dd);
  float4 cb = *(const float4*)(cache + t * 128 + dd + 4);
  u16x8 o;
  {
    float c = ca.x, s = ca.y, x0 = bf2f(v[0]), x1 = bf2f(v[1]);
    o[0] = f2bf(x0 * c - x1 * s); o[1] = f2bf(x0 * s + x1 * c);
  }
  {
    float c = ca.z, s = ca.w, x0 = bf2f(v[2]), x1 = bf2f(v[3]);
    o[2] = f2bf(x0 * c - x1 * s); o[3] = f2bf(x0 * s + x1 * c);
  }
  {
    float c = cb.x, s = cb.y, x0 = bf2f(v[4]), x1 = bf2f(v[5]);
    o[4] = f2bf(x0 * c - x1 * s); o[5] = f2bf(x0 * s + x1 * c);
  }
  {
    float c = cb.z, s = cb.w, x0 = bf2f(v[6]), x1 = bf2f(v[7]);
    o[6] = f2bf(x0 * c - x1 * s); o[7] = f2bf(x0 * s + x1 * c);
  }
  *(u16x8*)(K2 + (long)bk * 524288 + (long)r * 8) = o;
}

// ---------------- V rearrange via LDS transpose (coalesced both sides) ----------------
// V2[bk][kc=key/128][jd=d/16][ks=(key%128)/32][q4][l16=d%16][e=key%8]
__global__ __launch_bounds__(256) void vrearr2(const u16* __restrict__ qkv,
                                               u16* __restrict__ V2) {
  const int bid = blockIdx.x;          // 0..255
  const int bk = bid >> 5, kc = bid & 31;
  const int bb = bk >> 2, kv = bk & 3;
  const int t = threadIdx.x;
  __shared__ u16 L[128 * 136];         // [key][d], pad 8 u16 (16B-aligned rows)
  {
    int key = t >> 1;
    int dh = (t & 1) * 64;
    const u16* src = qkv + ((long)(bb * T_ + kc * 128 + key)) * 3072 + 2560 + kv * HD + dh;
    u16* dst = L + key * 136 + dh;
#pragma unroll
    for (int u = 0; u < 8; u++)
      *(u16x8*)(dst + u * 8) = *(const u16x8*)(src + u * 8);
  }
  __syncthreads();
  u16* out = V2 + (long)bk * 524288 + (long)kc * 16384;
#pragma unroll
  for (int step = 0; step < 8; step++) {
    int o = step * 256 + t;            // 0..2047
    int l16 = o & 15, q4 = (o >> 4) & 3, ks = (o >> 6) & 3, jd = (o >> 8) & 7;
    int keyb = ks * 32 + q4 * 8;
    int d = jd * 16 + l16;
    u16x8 v;
#pragma unroll
    for (int e = 0; e < 8; e++) v[e] = L[(keyb + e) * 136 + d];
    *(u16x8*)(out + (long)o * 8) = v;
  }
}

// ---------------- bf16 GEMM: C[M][N] = A[M][K] * B[N][K]^T ----------------
// 256x256 tile, BK=64, 8 waves (2M x 4N), double-buffered 128 KiB LDS.
// READ-AHEAD pipeline, 2 barriers per K-tile (proven 117.7 us at R10).
#define GBAR() __builtin_amdgcn_s_barrier()
#define LGKM0() do { asm volatile("s_waitcnt lgkmcnt(0)" ::: "memory"); \
                     __builtin_amdgcn_sched_barrier(0); } while (0)

template <int WRITE_BF16>
__global__ __launch_bounds__(512, 2) void gemm256(const u16* __restrict__ A,
                                                  const u16* __restrict__ Bw,
                                                  void* __restrict__ Cv,
                                                  int M, int N, int K) {
  __shared__ __align__(16) u16 lds[65536];   // 128 KiB
  const int tid = threadIdx.x;
  const int lane = tid & 63;
  const int wave = tid >> 6;
  const int q4 = lane >> 4, l16 = lane & 15;
  const int wm = wave >> 2, wn = wave & 3;

  // bijective XCD swizzle (launcher guarantees nwg % 8 == 0)
  const int nwg = gridDim.x * gridDim.y;
  const int orig = blockIdx.y * gridDim.x + blockIdx.x;
  const int swz = (orig & 7) * (nwg >> 3) + (orig >> 3);
  const int bm = swz / gridDim.x, bn = swz % gridDim.x;
  const long m0 = (long)bm * 256, n0 = (long)bn * 256;

  // ---- staging addressing: thread t -> LDS linear t*16 bytes (+8192) ----
  const int srow = tid >> 2;            // 0..127  (second load: +128)
  const int slot = tid & 3;
  const int sx = (slot ^ ((srow >> 1) & 3)) * 8;   // (srow+128) gives same XOR
  const u16* Ag0 = A + (m0 + srow) * K + sx;
  const u16* Ag1 = A + (m0 + srow + 128) * K + sx;
  const u16* Bg0 = Bw + (n0 + srow) * K + sx;
  const u16* Bg1 = Bw + (n0 + srow + 128) * K + sx;
  u16* ldst = lds + tid * 8;            // u16 units

  const int nkt = K >> 6;

#define STAGE_A(bufi, kh, kt)                                  \
  do {                                                         \
    long ko = ((long)(kt) << 6) + ((kh) << 5);                 \
    u16* d = ldst + (bufi) * 32768 + (kh) * 8192;              \
    gload_lds16(Ag0 + ko, d);                                  \
    gload_lds16(Ag1 + ko, d + 4096);                           \
  } while (0)
#define STAGE_B(bufi, kh, kt)                                  \
  do {                                                         \
    long ko = ((long)(kt) << 6) + ((kh) << 5);                 \
    u16* d = ldst + (bufi) * 32768 + 16384 + (kh) * 8192;      \
    gload_lds16(Bg0 + ko, d);                                  \
    gload_lds16(Bg1 + ko, d + 4096);                           \
  } while (0)

  // fragment LDS offsets (u16 units) for kh=0; kh=1 adds 8192.
  int offA[8], offB[4];
#pragma unroll
  for (int m = 0; m < 8; m++) {
    int r = wm * 128 + m * 16 + l16;
    offA[m] = r * 32 + ((q4 ^ ((r >> 1) & 3)) << 3);
  }
#pragma unroll
  for (int n = 0; n < 4; n++) {
    int r = wn * 64 + n * 16 + l16;
    offB[n] = 16384 + r * 32 + ((q4 ^ ((r >> 1) & 3)) << 3);
  }

  f32x4 acc[8][4] = {};

  // ---- prologue: tile0 (4 half-stages) + tile1 k0 (2 half-stages) ----
  STAGE_A(0, 0, 0); STAGE_B(0, 0, 0); STAGE_A(0, 1, 0); STAGE_B(0, 1, 0);
  if (nkt > 1) {
    STAGE_A(1, 0, 1); STAGE_B(1, 0, 1);
    asm volatile("s_waitcnt vmcnt(4)" ::: "memory");
  } else {
    asm volatile("s_waitcnt vmcnt(0)" ::: "memory");
  }
  GBAR();

  bf16x8 afX[4], afY[4], bvA[4], bvB[4];
  for (int kt = 0; kt < nkt; kt++) {
    const int bo = (kt & 1) * 32768;    // current read buffer offset (u16)
    // ---- P1: R1 (cold) ; stage A-k1 ; wait ; R2 under MFMA ----
#pragma unroll
    for (int m = 0; m < 4; m++) afX[m] = *(const bf16x8*)(lds + bo + offA[m]);
#pragma unroll
    for (int n = 0; n < 4; n++) bvA[n] = *(const bf16x8*)(lds + bo + offB[n]);
    if (kt + 1 < nkt) STAGE_A((kt + 1) & 1, 1, kt + 1);
    LGKM0();
#pragma unroll
    for (int m = 0; m < 4; m++) afY[m] = *(const bf16x8*)(lds + bo + offA[4 + m]);
    __builtin_amdgcn_s_setprio(1);
#pragma unroll
    for (int m = 0; m < 4; m++)
#pragma unroll
      for (int n = 0; n < 4; n++)
        acc[m][n] = __builtin_amdgcn_mfma_f32_16x16x32_bf16(afX[m], bvA[n], acc[m][n], 0, 0, 0);
    __builtin_amdgcn_s_setprio(0);
    // ---- P2: stage B-k1 ; wait R2 ; R3 under MFMA ; mid-BAR ----
    if (kt + 1 < nkt) STAGE_B((kt + 1) & 1, 1, kt + 1);
    LGKM0();
#pragma unroll
    for (int m = 0; m < 4; m++) afX[m] = *(const bf16x8*)(lds + bo + 8192 + offA[m]);
#pragma unroll
    for (int n = 0; n < 4; n++) bvB[n] = *(const bf16x8*)(lds + bo + 8192 + offB[n]);
    __builtin_amdgcn_s_setprio(1);
#pragma unroll
    for (int m = 0; m < 4; m++)
#pragma unroll
      for (int n = 0; n < 4; n++)
        acc[4 + m][n] = __builtin_amdgcn_mfma_f32_16x16x32_bf16(afY[m], bvA[n], acc[4 + m][n], 0, 0, 0);
    __builtin_amdgcn_s_setprio(0);
    GBAR();                              // k0 globally consumed -> reusable
    // ---- P3: stage A-k0(kt+2) into cur ; wait R3 ; R4 under MFMA ----
    if (kt + 2 < nkt) STAGE_A(kt & 1, 0, kt + 2);
    LGKM0();
#pragma unroll
    for (int m = 0; m < 4; m++) afY[m] = *(const bf16x8*)(lds + bo + 8192 + offA[4 + m]);
    __builtin_amdgcn_s_setprio(1);
#pragma unroll
    for (int m = 0; m < 4; m++)
#pragma unroll
      for (int n = 0; n < 4; n++)
        acc[m][n] = __builtin_amdgcn_mfma_f32_16x16x32_bf16(afX[m], bvB[n], acc[m][n], 0, 0, 0);
    __builtin_amdgcn_s_setprio(0);
    // ---- P4: stage B-k0(kt+2) ; wait R4 ; MFMA ; counted vmcnt ; BAR ----
    if (kt + 2 < nkt) STAGE_B(kt & 1, 0, kt + 2);
    LGKM0();
    __builtin_amdgcn_s_setprio(1);
#pragma unroll
    for (int m = 0; m < 4; m++)
#pragma unroll
      for (int n = 0; n < 4; n++)
        acc[4 + m][n] = __builtin_amdgcn_mfma_f32_16x16x32_bf16(afY[m], bvB[n], acc[4 + m][n], 0, 0, 0);
    __builtin_amdgcn_s_setprio(0);
    if (kt + 2 < nkt)
      asm volatile("s_waitcnt vmcnt(4)" ::: "memory");
    else
      asm volatile("s_waitcnt vmcnt(0)" ::: "memory");
    GBAR();
  }
#undef STAGE_A
#undef STAGE_B

  // ---- epilogue: C write (C/D frag: row=q4*4+r, col=l16) ----
  const long crow0 = m0 + wm * 128;
  const long ccol0 = n0 + wn * 64;
#pragma unroll
  for (int m = 0; m < 8; m++)
#pragma unroll
    for (int n = 0; n < 4; n++)
#pragma unroll
      for (int r = 0; r < 4; r++) {
        long row = crow0 + m * 16 + q4 * 4 + r;
        if (WRITE_BF16)
          ((u16*)Cv)[row * (long)N + ccol0 + n * 16 + l16] = f2bf(acc[m][n][r]);
        else
          ((float*)Cv)[row * (long)N + ccol0 + n * 16 + l16] = acc[m][n][r];
      }
}

// ---------------- sliding-window attention (R9 structure) + fused Q-RoPE ----------------
//  * 256-row q-tile, 512 threads / 8 waves -> 512 blocks, 1 block/CU (132 KB).
//  * K and V staged in LDS via async global_load_lds; counted vmcnt(4) twice
//    per chunk (no cold drains).
//  * Band-liveness skip at 32-key granularity, identical sets for QK and PV.
//  * XCD swizzle: 64 blocks/XCD = one (b,kvh) -> 2 MB K2/V2 L2-pinned.
//  * R11: Q-rope fused into the qf load (pair = adjacent e in-register;
//    scale*log2e folded into c,s exactly as the old rope_kernel -> bit-identical).
__global__ __launch_bounds__(512, 2) void attn_kernel(const u16* __restrict__ qkv,
                                                      const u16* __restrict__ K2,
                                                      const u16* __restrict__ V2,
                                                      u16* __restrict__ y,
                                                      const float* __restrict__ rope) {
  const int lin = blockIdx.x + (int)gridDim.x * (blockIdx.y + (int)gridDim.y * blockIdx.z);
  const int swz = (lin & 7) * 64 + (lin >> 3);   // bijective: 512 = 8*64
  const int tc = swz & 15, h = (swz >> 4) & 15, b = swz >> 8;
  const int t0 = tc * 256;
  const int kvh = h >> 2;
  __shared__ __align__(16) u16 Kl[16384];        // 32 KB staged K chunk
  __shared__ __align__(16) u16 Vl[16384];        // 32 KB staged V chunk
  __shared__ u16 Pl[8 * 32 * 136];               // 69.6 KB wave-private P
  const int tid = threadIdx.x, wave = tid >> 6, lane = tid & 63;
  const int q4 = lane >> 4, l16 = lane & 15;
  u16* Pw = Pl + wave * (32 * 136);
  const int wq0 = t0 + 32 * wave;                // wave's first q row

  bf16x8 qf[2][4];
#pragma unroll
  for (int i = 0; i < 2; i++) {
    const int t = wq0 + 16 * i + l16;
#pragma unroll
    for (int ks = 0; ks < 4; ks++) {
      bf16x8 v = *(const bf16x8*)(qkv +
          ((long)(b * T_ + t)) * 3072 + h * HD + ks * 32 + q4 * 8);
      const int dd = ks * 32 + q4 * 8;
      float4 ca = *(const float4*)(rope + t * 128 + dd);
      float4 cb = *(const float4*)(rope + t * 128 + dd + 4);
      const float SC = 0.1275174315f;            // 1/sqrt(D) * log2(e)
      bf16x8 o;
      {
        float c = ca.x * SC, s = ca.y * SC;
        float x0 = bf2f((u16)v[0]), x1 = bf2f((u16)v[1]);
        o[0] = (short)f2bf(x0 * c - x1 * s); o[1] = (short)f2bf(x0 * s + x1 * c);
      }
      {
        float c = ca.z * SC, s = ca.w * SC;
        float x0 = bf2f((u16)v[2]), x1 = bf2f((u16)v[3]);
        o[2] = (short)f2bf(x0 * c - x1 * s); o[3] = (short)f2bf(x0 * s + x1 * c);
      }
      {
        float c = cb.x * SC, s = cb.y * SC;
        float x0 = bf2f((u16)v[4]), x1 = bf2f((u16)v[5]);
        o[4] = (short)f2bf(x0 * c - x1 * s); o[5] = (short)f2bf(x0 * s + x1 * c);
      }
      {
        float c = cb.z * SC, s = cb.w * SC;
        float x0 = bf2f((u16)v[6]), x1 = bf2f((u16)v[7]);
        o[6] = (short)f2bf(x0 * c - x1 * s); o[7] = (short)f2bf(x0 * s + x1 * c);
      }
      qf[i][ks] = o;
    }
  }

  f32x4 O[2][8] = {};
  float l_i[2][4] = {};

  const u16* KB = K2 + (long)(b * NKV + kvh) * 524288;
  const u16* VB = V2 + (long)(b * NKV + kvh) * 524288;

  int kstart = t0 - 256; if (kstart < 0) kstart = 0;
  const int kend = t0 + 128;                     // rows t0..t0+255 need keys to t0+255

  // prologue: issue K(kstart)
  {
    const u16* Kg = KB + ((long)(kstart >> 4)) * 2048;
#pragma unroll
    for (int i = 0; i < 4; i++)
      gload_lds16(Kg + i * 4096 + tid * 8, Kl + i * 4096 + tid * 8);
  }

  for (int k0 = kstart; k0 <= kend; k0 += 128) {
    // 1. issue V(k0)  (Vl free: prev PV reads fenced by trailing barrier)
    {
      const u16* Vg = VB + ((long)(k0 >> 7)) * 16384;
#pragma unroll
      for (int i = 0; i < 4; i++)
        gload_lds16(Vg + i * 4096 + tid * 8, Vl + i * 4096 + tid * 8);
    }
    // 2-3. wait K(k0) (4 newest = V), make visible
    asm volatile("s_waitcnt vmcnt(4)" ::: "memory");
    GBAR();
    // 4. QK for live 32-key chunks; P -> wave-private LDS
    const int dbase0 = wq0 + q4 * 4 - k0 - l16;
#pragma unroll
    for (int kc = 0; kc < 4; kc++) {
      const bool live = (k0 + 32 * kc <= wq0 + 31) && (k0 + 32 * kc + 31 >= wq0 - 255);
      if (!live) continue;
#pragma unroll
      for (int jh = 0; jh < 2; jh++) {
        const int j = kc * 2 + jh;
        bf16x8 kf[4];
#pragma unroll
        for (int ks = 0; ks < 4; ks++)
          kf[ks] = *(const bf16x8*)(Kl + j * 2048 + ks * 512 + lane * 8);
        f32x4 s0 = {}, s1 = {};
#pragma unroll
        for (int ks = 0; ks < 4; ks++) {
          s0 = __builtin_amdgcn_mfma_f32_16x16x32_bf16(qf[0][ks], kf[ks], s0, 0, 0, 0);
          s1 = __builtin_amdgcn_mfma_f32_16x16x32_bf16(qf[1][ks], kf[ks], s1, 0, 0, 0);
        }
#pragma unroll
        for (int r = 0; r < 4; r++) {
          int d0 = dbase0 + r - 16 * j;               // q - k for i=0
          float p0 = __builtin_amdgcn_exp2f(s0[r]);
          p0 = ((unsigned)d0 <= 255u) ? p0 : 0.f;     // band mask
          l_i[0][r] += p0;
          Pw[(q4 * 4 + r) * 136 + 16 * j + l16] = f2bf(p0);
          int d1 = d0 + 16;                            // i=1
          float p1 = __builtin_amdgcn_exp2f(s1[r]);
          p1 = ((unsigned)d1 <= 255u) ? p1 : 0.f;
          l_i[1][r] += p1;
          Pw[(16 + q4 * 4 + r) * 136 + 16 * j + l16] = f2bf(p1);
        }
      }
    }
    // 5. all waves done reading Kl -> safe to restage
    GBAR();
    // 6-7. issue K(next); wait V (4 newest = next-K)
    if (k0 + 128 <= kend) {
      const u16* Kg = KB + ((long)((k0 + 128) >> 4)) * 2048;
#pragma unroll
      for (int i = 0; i < 4; i++)
        gload_lds16(Kg + i * 4096 + tid * 8, Kl + i * 4096 + tid * 8);
      asm volatile("s_waitcnt vmcnt(4)" ::: "memory");
    } else {
      asm volatile("s_waitcnt vmcnt(0)" ::: "memory");
    }
    // 8. V visible
    GBAR();
    // 9. PV for live chunks (same liveness as QK -> P fully defined)
#pragma unroll
    for (int ks = 0; ks < 4; ks++) {
      const bool live = (k0 + 32 * ks <= wq0 + 31) && (k0 + 32 * ks + 31 >= wq0 - 255);
      if (!live) continue;
      bf16x8 pf0 = *(const bf16x8*)(&Pw[l16 * 136 + ks * 32 + q4 * 8]);
      bf16x8 pf1 = *(const bf16x8*)(&Pw[(16 + l16) * 136 + ks * 32 + q4 * 8]);
#pragma unroll
      for (int jd = 0; jd < 8; jd++) {
        bf16x8 vf = *(const bf16x8*)(Vl + (jd * 4 + ks) * 512 + lane * 8);
        O[0][jd] = __builtin_amdgcn_mfma_f32_16x16x32_bf16(pf0, vf, O[0][jd], 0, 0, 0);
        O[1][jd] = __builtin_amdgcn_mfma_f32_16x16x32_bf16(pf1, vf, O[1][jd], 0, 0, 0);
      }
    }
    // 10. all waves done reading Vl -> next V-issue safe
    GBAR();
  }
  // ---- finalize: reduce l across the 16-lane row groups, divide, store ----
#pragma unroll
  for (int d = 1; d < 16; d <<= 1)
#pragma unroll
    for (int i = 0; i < 2; i++)
#pragma unroll
      for (int r = 0; r < 4; r++)
        l_i[i][r] += __shfl_xor(l_i[i][r], d, 64);
#pragma unroll
  for (int i = 0; i < 2; i++)
#pragma unroll
    for (int r = 0; r < 4; r++) {
      float inv = 1.0f / l_i[i][r];
      long row = (long)(b * T_ + wq0 + 16 * i + q4 * 4 + r);
#pragma unroll
      for (int jd = 0; jd < 8; jd++)
        y[row * 2048 + h * HD + 16 * jd + l16] = f2bf(O[i][jd][r] * inv);
    }
}

// ---------------- launcher ----------------
extern "C" void kernel_launch(void* const* d_in, const int* in_sizes, int n_in,
                              void* d_out, int out_size, void* d_ws, size_t ws_size,
                              hipStream_t stream) {
  const float* x    = (const float*)d_in[0];
  const float* wq   = (const float*)d_in[1];
  const float* wk   = (const float*)d_in[2];
  const float* wv   = (const float*)d_in[3];
  const float* wo   = (const float*)d_in[4];
  const float* rope = (const float*)d_in[5];
  float* out = (float*)d_out;

  u16* xb   = (u16*)d_ws;                       // 8192*2048
  u16* wqkv = xb + (long)8192 * 2048;           // 3072*2048
  u16* wob  = wqkv + (long)3072 * 2048;         // 2048*2048
  u16* qkv  = wob + (long)2048 * 2048;          // 8192*3072
  u16* V2   = qkv + (long)8192 * 3072;          // 4.19M el
  u16* K2   = wqkv;                             // alias: wqkv dead after gemm1
  u16* yb   = xb;                               // reuse

  // one fused convert pass: 27262976 elements = 26624 blocks * 1024 el
  cvt_all<<<dim3(26624), dim3(256), 0, stream>>>(x, wq, wk, wv, wo, xb, wqkv, wob);

  // GEMM1 (plain): qkv = x @ wqkv^T  (unroped; consumers apply rope)
  gemm256<1><<<dim3(3072 / 256, 8192 / 256), dim3(512), 0, stream>>>(
      xb, wqkv, (void*)qkv, 8192, 3072, 2048);

  // K rearrange + fused K-rope ; V rearrange (no rope)
  krearr<<<dim3(2048), dim3(256), 0, stream>>>(qkv, K2, rope);
  vrearr2<<<dim3(256), dim3(256), 0, stream>>>(qkv, V2);

  // attention with fused Q-rope
  attn_kernel<<<dim3(T_ / 256, NH, B_), dim3(512), 0, stream>>>(qkv, K2, V2, yb, rope);

  gemm256<0><<<dim3(2048 / 256, 8192 / 256), dim3(512), 0, stream>>>(
      yb, wob, (void*)out, 8192, 2048, 2048);
}

// Round 12
// 389.186 us; speedup vs baseline: 1.0588x; 1.0170x over previous
//
#include <hip/hip_runtime.h>
#include <stdint.h>

typedef unsigned short u16;
typedef __attribute__((ext_vector_type(8))) short bf16x8;      // 8 bf16 = 4 VGPRs
typedef __attribute__((ext_vector_type(8))) unsigned short u16x8;
typedef __attribute__((ext_vector_type(4))) float f32x4;

#define B_  2
#define T_  4096
#define C_  2048
#define NH  16
#define NKV 4
#define HD  128

__device__ __forceinline__ u16 f2bf(float f) {
  union { float f; uint32_t u; } v; v.f = f;
  uint32_t u = v.u;
  u += 0x7fffu + ((u >> 16) & 1u);   // RNE
  return (u16)(u >> 16);
}
__device__ __forceinline__ float bf2f(u16 h) {
  union { uint32_t u; float f; } v; v.u = ((uint32_t)h) << 16;
  return v.f;
}

__device__ __forceinline__ void gload_lds16(const u16* g, u16* l) {
  __builtin_amdgcn_global_load_lds(
      (const __attribute__((address_space(1))) void*)g,
      (__attribute__((address_space(3))) void*)l, 16, 0, 0);
}

// ---------------- fused f32 -> bf16 convert (x, wq, wk, wv, wo in one grid) ----------------
__global__ void cvt_all(const float* __restrict__ x, const float* __restrict__ wq,
                        const float* __restrict__ wk, const float* __restrict__ wv,
                        const float* __restrict__ wo, u16* __restrict__ xb,
                        u16* __restrict__ wqkv, u16* __restrict__ wob) {
  long i = ((long)blockIdx.x * 256 + threadIdx.x) * 4;
  const float* src; u16* dst; long off;
  if (i < 16777216L)      { src = x;  dst = xb;              off = i; }
  else if (i < 20971520L) { src = wq; dst = wqkv;            off = i - 16777216L; }
  else if (i < 22020096L) { src = wk; dst = wqkv + 4194304L; off = i - 20971520L; }
  else if (i < 23068672L) { src = wv; dst = wqkv + 5242880L; off = i - 22020096L; }
  else                    { src = wo; dst = wob;             off = i - 23068672L; }
  float4 v = *(const float4*)(src + off);
  ushort4 o4;
  o4.x = f2bf(v.x); o4.y = f2bf(v.y); o4.z = f2bf(v.z); o4.w = f2bf(v.w);
  *(ushort4*)(dst + off) = o4;
}

// ---------------- K rearrange + fused K-RoPE (R12: LDS rope broadcast) ----------------
// K2[bk][kb=key/16][ks=d/32][q4][l16=key%16][e=d%8]
// Each block covers ONE kb (16 rows); its 16x128 f32 rope slice (8 KB) is
// staged into LDS coalescedly, then broadcast-read (padded stride 132 ->
// <=2-way banks). Replaces per-thread 64-line stride-512B global gathers.
__global__ __launch_bounds__(256) void krearr(const u16* __restrict__ qkv,
                                              u16* __restrict__ K2,
                                              const float* __restrict__ cache) {
  __shared__ float Lc[16 * 132];
  int gid = blockIdx.x * 256 + threadIdx.x;
  int r = gid & 65535, bk = gid >> 16;
  int l16 = r & 15, q4 = (r >> 4) & 3, ks = (r >> 6) & 3, kb = r >> 8;
  int bb = bk >> 2, kv = bk & 3;
  {
    int row = threadIdx.x >> 4;          // 0..15
    int c0  = (threadIdx.x & 15) * 8;    // 0..120
    const float* s = cache + (long)(kb * 16 + row) * 128 + c0;
    float4 a = *(const float4*)s;
    float4 b4 = *(const float4*)(s + 4);
    *(float4*)(Lc + row * 132 + c0) = a;
    *(float4*)(Lc + row * 132 + c0 + 4) = b4;
  }
  __syncthreads();
  int t = kb * 16 + l16;
  int dd = ks * 32 + q4 * 8;
  const u16* src = qkv + ((long)(bb * T_ + t)) * 3072 + 2048 + kv * HD + dd;
  u16x8 v = *(const u16x8*)src;
  const float* cl = Lc + l16 * 132 + dd;
  u16x8 o;
#pragma unroll
  for (int p = 0; p < 4; p++) {
    float c = cl[2 * p], s = cl[2 * p + 1];
    float x0 = bf2f(v[2 * p]), x1 = bf2f(v[2 * p + 1]);
    o[2 * p]     = f2bf(x0 * c - x1 * s);
    o[2 * p + 1] = f2bf(x0 * s + x1 * c);
  }
  *(u16x8*)(K2 + (long)bk * 524288 + (long)r * 8) = o;
}

// ---------------- V rearrange via LDS transpose (coalesced both sides) ----------------
// V2[bk][kc=key/128][jd=d/16][ks=(key%128)/32][q4][l16=d%16][e=key%8]
__global__ __launch_bounds__(256) void vrearr2(const u16* __restrict__ qkv,
                                               u16* __restrict__ V2) {
  const int bid = blockIdx.x;          // 0..255
  const int bk = bid >> 5, kc = bid & 31;
  const int bb = bk >> 2, kv = bk & 3;
  const int t = threadIdx.x;
  __shared__ u16 L[128 * 136];         // [key][d], pad 8 u16 (16B-aligned rows)
  {
    int key = t >> 1;
    int dh = (t & 1) * 64;
    const u16* src = qkv + ((long)(bb * T_ + kc * 128 + key)) * 3072 + 2560 + kv * HD + dh;
    u16* dst = L + key * 136 + dh;
#pragma unroll
    for (int u = 0; u < 8; u++)
      *(u16x8*)(dst + u * 8) = *(const u16x8*)(src + u * 8);
  }
  __syncthreads();
  u16* out = V2 + (long)bk * 524288 + (long)kc * 16384;
#pragma unroll
  for (int step = 0; step < 8; step++) {
    int o = step * 256 + t;            // 0..2047
    int l16 = o & 15, q4 = (o >> 4) & 3, ks = (o >> 6) & 3, jd = (o >> 8) & 7;
    int keyb = ks * 32 + q4 * 8;
    int d = jd * 16 + l16;
    u16x8 v;
#pragma unroll
    for (int e = 0; e < 8; e++) v[e] = L[(keyb + e) * 136 + d];
    *(u16x8*)(out + (long)o * 8) = v;
  }
}

// ---------------- bf16 GEMM: C[M][N] = A[M][K] * B[N][K]^T ----------------
// 256x256 tile, BK=64, 8 waves (2M x 4N), double-buffered 128 KiB LDS.
// READ-AHEAD pipeline, 2 barriers per K-tile.
// R12: removed the explicit lgkmcnt(0)+sched_barrier before each MFMA burst.
// The ds_reads are PLAIN loads -> the compiler inserts fine-grained lgkmcnt(N)
// per consumed operand (m97 evidence), letting MFMA[i] start while later reads
// are still in flight and letting the scheduler interleave reads into the
// burst. (Rule #18's fence is only needed for inline-asm ds_reads.) The
// "memory"-clobbered vmcnt/barrier asm still orders all LDS accesses.
#define GBAR() __builtin_amdgcn_s_barrier()

template <int WRITE_BF16>
__global__ __launch_bounds__(512, 2) void gemm256(const u16* __restrict__ A,
                                                  const u16* __restrict__ Bw,
                                                  void* __restrict__ Cv,
                                                  int M, int N, int K) {
  __shared__ __align__(16) u16 lds[65536];   // 128 KiB
  const int tid = threadIdx.x;
  const int lane = tid & 63;
  const int wave = tid >> 6;
  const int q4 = lane >> 4, l16 = lane & 15;
  const int wm = wave >> 2, wn = wave & 3;

  // bijective XCD swizzle (launcher guarantees nwg % 8 == 0)
  const int nwg = gridDim.x * gridDim.y;
  const int orig = blockIdx.y * gridDim.x + blockIdx.x;
  const int swz = (orig & 7) * (nwg >> 3) + (orig >> 3);
  const int bm = swz / gridDim.x, bn = swz % gridDim.x;
  const long m0 = (long)bm * 256, n0 = (long)bn * 256;

  // ---- staging addressing: thread t -> LDS linear t*16 bytes (+8192) ----
  const int srow = tid >> 2;            // 0..127  (second load: +128)
  const int slot = tid & 3;
  const int sx = (slot ^ ((srow >> 1) & 3)) * 8;   // (srow+128) gives same XOR
  const u16* Ag0 = A + (m0 + srow) * K + sx;
  const u16* Ag1 = A + (m0 + srow + 128) * K + sx;
  const u16* Bg0 = Bw + (n0 + srow) * K + sx;
  const u16* Bg1 = Bw + (n0 + srow + 128) * K + sx;
  u16* ldst = lds + tid * 8;            // u16 units

  const int nkt = K >> 6;

#define STAGE_A(bufi, kh, kt)                                  \
  do {                                                         \
    long ko = ((long)(kt) << 6) + ((kh) << 5);                 \
    u16* d = ldst + (bufi) * 32768 + (kh) * 8192;              \
    gload_lds16(Ag0 + ko, d);                                  \
    gload_lds16(Ag1 + ko, d + 4096);                           \
  } while (0)
#define STAGE_B(bufi, kh, kt)                                  \
  do {                                                         \
    long ko = ((long)(kt) << 6) + ((kh) << 5);                 \
    u16* d = ldst + (bufi) * 32768 + 16384 + (kh) * 8192;      \
    gload_lds16(Bg0 + ko, d);                                  \
    gload_lds16(Bg1 + ko, d + 4096);                           \
  } while (0)

  // fragment LDS offsets (u16 units) for kh=0; kh=1 adds 8192.
  int offA[8], offB[4];
#pragma unroll
  for (int m = 0; m < 8; m++) {
    int r = wm * 128 + m * 16 + l16;
    offA[m] = r * 32 + ((q4 ^ ((r >> 1) & 3)) << 3);
  }
#pragma unroll
  for (int n = 0; n < 4; n++) {
    int r = wn * 64 + n * 16 + l16;
    offB[n] = 16384 + r * 32 + ((q4 ^ ((r >> 1) & 3)) << 3);
  }

  f32x4 acc[8][4] = {};

  // ---- prologue: tile0 (4 half-stages) + tile1 k0 (2 half-stages) ----
  STAGE_A(0, 0, 0); STAGE_B(0, 0, 0); STAGE_A(0, 1, 0); STAGE_B(0, 1, 0);
  if (nkt > 1) {
    STAGE_A(1, 0, 1); STAGE_B(1, 0, 1);
    asm volatile("s_waitcnt vmcnt(4)" ::: "memory");
  } else {
    asm volatile("s_waitcnt vmcnt(0)" ::: "memory");
  }
  GBAR();

  bf16x8 afX[4], afY[4], bvA[4], bvB[4];
  for (int kt = 0; kt < nkt; kt++) {
    const int bo = (kt & 1) * 32768;    // current read buffer offset (u16)
    // ---- P1: R1 reads ; stage A-k1 ; R2 reads ; MFMA (compiler-scheduled waits) ----
#pragma unroll
    for (int m = 0; m < 4; m++) afX[m] = *(const bf16x8*)(lds + bo + offA[m]);
#pragma unroll
    for (int n = 0; n < 4; n++) bvA[n] = *(const bf16x8*)(lds + bo + offB[n]);
    if (kt + 1 < nkt) STAGE_A((kt + 1) & 1, 1, kt + 1);
#pragma unroll
    for (int m = 0; m < 4; m++) afY[m] = *(const bf16x8*)(lds + bo + offA[4 + m]);
    __builtin_amdgcn_s_setprio(1);
#pragma unroll
    for (int m = 0; m < 4; m++)
#pragma unroll
      for (int n = 0; n < 4; n++)
        acc[m][n] = __builtin_amdgcn_mfma_f32_16x16x32_bf16(afX[m], bvA[n], acc[m][n], 0, 0, 0);
    __builtin_amdgcn_s_setprio(0);
    // ---- P2: stage B-k1 ; R3 reads ; MFMA ; mid-BAR ----
    if (kt + 1 < nkt) STAGE_B((kt + 1) & 1, 1, kt + 1);
#pragma unroll
    for (int m = 0; m < 4; m++) afX[m] = *(const bf16x8*)(lds + bo + 8192 + offA[m]);
#pragma unroll
    for (int n = 0; n < 4; n++) bvB[n] = *(const bf16x8*)(lds + bo + 8192 + offB[n]);
    __builtin_amdgcn_s_setprio(1);
#pragma unroll
    for (int m = 0; m < 4; m++)
#pragma unroll
      for (int n = 0; n < 4; n++)
        acc[4 + m][n] = __builtin_amdgcn_mfma_f32_16x16x32_bf16(afY[m], bvA[n], acc[4 + m][n], 0, 0, 0);
    __builtin_amdgcn_s_setprio(0);
    GBAR();                              // k0 globally consumed -> reusable
    // ---- P3: stage A-k0(kt+2) into cur ; R4 reads ; MFMA ----
    if (kt + 2 < nkt) STAGE_A(kt & 1, 0, kt + 2);
#pragma unroll
    for (int m = 0; m < 4; m++) afY[m] = *(const bf16x8*)(lds + bo + 8192 + offA[4 + m]);
    __builtin_amdgcn_s_setprio(1);
#pragma unroll
    for (int m = 0; m < 4; m++)
#pragma unroll
      for (int n = 0; n < 4; n++)
        acc[m][n] = __builtin_amdgcn_mfma_f32_16x16x32_bf16(afX[m], bvB[n], acc[m][n], 0, 0, 0);
    __builtin_amdgcn_s_setprio(0);
    // ---- P4: stage B-k0(kt+2) ; MFMA ; counted vmcnt ; BAR ----
    if (kt + 2 < nkt) STAGE_B(kt & 1, 0, kt + 2);
    __builtin_amdgcn_s_setprio(1);
#pragma unroll
    for (int m = 0; m < 4; m++)
#pragma unroll
      for (int n = 0; n < 4; n++)
        acc[4 + m][n] = __builtin_amdgcn_mfma_f32_16x16x32_bf16(afY[m], bvB[n], acc[4 + m][n], 0, 0, 0);
    __builtin_amdgcn_s_setprio(0);
    if (kt + 2 < nkt)
      asm volatile("s_waitcnt vmcnt(4)" ::: "memory");
    else
      asm volatile("s_waitcnt vmcnt(0)" ::: "memory");
    GBAR();
  }
#undef STAGE_A
#undef STAGE_B

  // ---- epilogue: C write (C/D frag: row=q4*4+r, col=l16) ----
  const long crow0 = m0 + wm * 128;
  const long ccol0 = n0 + wn * 64;
#pragma unroll
  for (int m = 0; m < 8; m++)
#pragma unroll
    for (int n = 0; n < 4; n++)
#pragma unroll
      for (int r = 0; r < 4; r++) {
        long row = crow0 + m * 16 + q4 * 4 + r;
        if (WRITE_BF16)
          ((u16*)Cv)[row * (long)N + ccol0 + n * 16 + l16] = f2bf(acc[m][n][r]);
        else
          ((float*)Cv)[row * (long)N + ccol0 + n * 16 + l16] = acc[m][n][r];
      }
}

// ---------------- sliding-window attention (R9 structure) + fused Q-RoPE ----------------
__global__ __launch_bounds__(512, 2) void attn_kernel(const u16* __restrict__ qkv,
                                                      const u16* __restrict__ K2,
                                                      const u16* __restrict__ V2,
                                                      u16* __restrict__ y,
                                                      const float* __restrict__ rope) {
  const int lin = blockIdx.x + (int)gridDim.x * (blockIdx.y + (int)gridDim.y * blockIdx.z);
  const int swz = (lin & 7) * 64 + (lin >> 3);   // bijective: 512 = 8*64
  const int tc = swz & 15, h = (swz >> 4) & 15, b = swz >> 8;
  const int t0 = tc * 256;
  const int kvh = h >> 2;
  __shared__ __align__(16) u16 Kl[16384];        // 32 KB staged K chunk
  __shared__ __align__(16) u16 Vl[16384];        // 32 KB staged V chunk
  __shared__ u16 Pl[8 * 32 * 136];               // 69.6 KB wave-private P
  const int tid = threadIdx.x, wave = tid >> 6, lane = tid & 63;
  const int q4 = lane >> 4, l16 = lane & 15;
  u16* Pw = Pl + wave * (32 * 136);
  const int wq0 = t0 + 32 * wave;                // wave's first q row

  bf16x8 qf[2][4];
#pragma unroll
  for (int i = 0; i < 2; i++) {
    const int t = wq0 + 16 * i + l16;
#pragma unroll
    for (int ks = 0; ks < 4; ks++) {
      bf16x8 v = *(const bf16x8*)(qkv +
          ((long)(b * T_ + t)) * 3072 + h * HD + ks * 32 + q4 * 8);
      const int dd = ks * 32 + q4 * 8;
      float4 ca = *(const float4*)(rope + t * 128 + dd);
      float4 cb = *(const float4*)(rope + t * 128 + dd + 4);
      const float SC = 0.1275174315f;            // 1/sqrt(D) * log2(e)
      bf16x8 o;
      {
        float c = ca.x * SC, s = ca.y * SC;
        float x0 = bf2f((u16)v[0]), x1 = bf2f((u16)v[1]);
        o[0] = (short)f2bf(x0 * c - x1 * s); o[1] = (short)f2bf(x0 * s + x1 * c);
      }
      {
        float c = ca.z * SC, s = ca.w * SC;
        float x0 = bf2f((u16)v[2]), x1 = bf2f((u16)v[3]);
        o[2] = (short)f2bf(x0 * c - x1 * s); o[3] = (short)f2bf(x0 * s + x1 * c);
      }
      {
        float c = cb.x * SC, s = cb.y * SC;
        float x0 = bf2f((u16)v[4]), x1 = bf2f((u16)v[5]);
        o[4] = (short)f2bf(x0 * c - x1 * s); o[5] = (short)f2bf(x0 * s + x1 * c);
      }
      {
        float c = cb.z * SC, s = cb.w * SC;
        float x0 = bf2f((u16)v[6]), x1 = bf2f((u16)v[7]);
        o[6] = (short)f2bf(x0 * c - x1 * s); o[7] = (short)f2bf(x0 * s + x1 * c);
      }
      qf[i][ks] = o;
    }
  }

  f32x4 O[2][8] = {};
  float l_i[2][4] = {};

  const u16* KB = K2 + (long)(b * NKV + kvh) * 524288;
  const u16* VB = V2 + (long)(b * NKV + kvh) * 524288;

  int kstart = t0 - 256; if (kstart < 0) kstart = 0;
  const int kend = t0 + 128;                     // rows t0..t0+255 need keys to t0+255

  // prologue: issue K(kstart)
  {
    const u16* Kg = KB + ((long)(kstart >> 4)) * 2048;
#pragma unroll
    for (int i = 0; i < 4; i++)
      gload_lds16(Kg + i * 4096 + tid * 8, Kl + i * 4096 + tid * 8);
  }

  for (int k0 = kstart; k0 <= kend; k0 += 128) {
    // 1. issue V(k0)  (Vl free: prev PV reads fenced by trailing barrier)
    {
      const u16* Vg = VB + ((long)(k0 >> 7)) * 16384;
#pragma unroll
      for (int i = 0; i < 4; i++)
        gload_lds16(Vg + i * 4096 + tid * 8, Vl + i * 4096 + tid * 8);
    }
    // 2-3. wait K(k0) (4 newest = V), make visible
    asm volatile("s_waitcnt vmcnt(4)" ::: "memory");
    GBAR();
    // 4. QK for live 32-key chunks; P -> wave-private LDS
    const int dbase0 = wq0 + q4 * 4 - k0 - l16;
#pragma unroll
    for (int kc = 0; kc < 4; kc++) {
      const bool live = (k0 + 32 * kc <= wq0 + 31) && (k0 + 32 * kc + 31 >= wq0 - 255);
      if (!live) continue;
#pragma unroll
      for (int jh = 0; jh < 2; jh++) {
        const int j = kc * 2 + jh;
        bf16x8 kf[4];
#pragma unroll
        for (int ks = 0; ks < 4; ks++)
          kf[ks] = *(const bf16x8*)(Kl + j * 2048 + ks * 512 + lane * 8);
        f32x4 s0 = {}, s1 = {};
#pragma unroll
        for (int ks = 0; ks < 4; ks++) {
          s0 = __builtin_amdgcn_mfma_f32_16x16x32_bf16(qf[0][ks], kf[ks], s0, 0, 0, 0);
          s1 = __builtin_amdgcn_mfma_f32_16x16x32_bf16(qf[1][ks], kf[ks], s1, 0, 0, 0);
        }
#pragma unroll
        for (int r = 0; r < 4; r++) {
          int d0 = dbase0 + r - 16 * j;               // q - k for i=0
          float p0 = __builtin_amdgcn_exp2f(s0[r]);
          p0 = ((unsigned)d0 <= 255u) ? p0 : 0.f;     // band mask
          l_i[0][r] += p0;
          Pw[(q4 * 4 + r) * 136 + 16 * j + l16] = f2bf(p0);
          int d1 = d0 + 16;                            // i=1
          float p1 = __builtin_amdgcn_exp2f(s1[r]);
          p1 = ((unsigned)d1 <= 255u) ? p1 : 0.f;
          l_i[1][r] += p1;
          Pw[(16 + q4 * 4 + r) * 136 + 16 * j + l16] = f2bf(p1);
        }
      }
    }
    // 5. all waves done reading Kl -> safe to restage
    GBAR();
    // 6-7. issue K(next); wait V (4 newest = next-K)
    if (k0 + 128 <= kend) {
      const u16* Kg = KB + ((long)((k0 + 128) >> 4)) * 2048;
#pragma unroll
      for (int i = 0; i < 4; i++)
        gload_lds16(Kg + i * 4096 + tid * 8, Kl + i * 4096 + tid * 8);
      asm volatile("s_waitcnt vmcnt(4)" ::: "memory");
    } else {
      asm volatile("s_waitcnt vmcnt(0)" ::: "memory");
    }
    // 8. V visible
    GBAR();
    // 9. PV for live chunks (same liveness as QK -> P fully defined)
#pragma unroll
    for (int ks = 0; ks < 4; ks++) {
      const bool live = (k0 + 32 * ks <= wq0 + 31) && (k0 + 32 * ks + 31 >= wq0 - 255);
      if (!live) continue;
      bf16x8 pf0 = *(const bf16x8*)(&Pw[l16 * 136 + ks * 32 + q4 * 8]);
      bf16x8 pf1 = *(const bf16x8*)(&Pw[(16 + l16) * 136 + ks * 32 + q4 * 8]);
#pragma unroll
      for (int jd = 0; jd < 8; jd++) {
        bf16x8 vf = *(const bf16x8*)(Vl + (jd * 4 + ks) * 512 + lane * 8);
        O[0][jd] = __builtin_amdgcn_mfma_f32_16x16x32_bf16(pf0, vf, O[0][jd], 0, 0, 0);
        O[1][jd] = __builtin_amdgcn_mfma_f32_16x16x32_bf16(pf1, vf, O[1][jd], 0, 0, 0);
      }
    }
    // 10. all waves done reading Vl -> next V-issue safe
    GBAR();
  }
  // ---- finalize: reduce l across the 16-lane row groups, divide, store ----
#pragma unroll
  for (int d = 1; d < 16; d <<= 1)
#pragma unroll
    for (int i = 0; i < 2; i++)
#pragma unroll
      for (int r = 0; r < 4; r++)
        l_i[i][r] += __shfl_xor(l_i[i][r], d, 64);
#pragma unroll
  for (int i = 0; i < 2; i++)
#pragma unroll
    for (int r = 0; r < 4; r++) {
      float inv = 1.0f / l_i[i][r];
      long row = (long)(b * T_ + wq0 + 16 * i + q4 * 4 + r);
#pragma unroll
      for (int jd = 0; jd < 8; jd++)
        y[row * 2048 + h * HD + 16 * jd + l16] = f2bf(O[i][jd][r] * inv);
    }
}

// ---------------- launcher ----------------
extern "C" void kernel_launch(void* const* d_in, const int* in_sizes, int n_in,
                              void* d_out, int out_size, void* d_ws, size_t ws_size,
                              hipStream_t stream) {
  const float* x    = (const float*)d_in[0];
  const float* wq   = (const float*)d_in[1];
  const float* wk   = (const float*)d_in[2];
  const float* wv   = (const float*)d_in[3];
  const float* wo   = (const float*)d_in[4];
  const float* rope = (const float*)d_in[5];
  float* out = (float*)d_out;

  u16* xb   = (u16*)d_ws;                       // 8192*2048
  u16* wqkv = xb + (long)8192 * 2048;           // 3072*2048
  u16* wob  = wqkv + (long)3072 * 2048;         // 2048*2048
  u16* qkv  = wob + (long)2048 * 2048;          // 8192*3072
  u16* V2   = qkv + (long)8192 * 3072;          // 4.19M el
  u16* K2   = wqkv;                             // alias: wqkv dead after gemm1
  u16* yb   = xb;                               // reuse

  // one fused convert pass: 27262976 elements = 26624 blocks * 1024 el
  cvt_all<<<dim3(26624), dim3(256), 0, stream>>>(x, wq, wk, wv, wo, xb, wqkv, wob);

  // GEMM1 (plain): qkv = x @ wqkv^T  (unroped; consumers apply rope)
  gemm256<1><<<dim3(3072 / 256, 8192 / 256), dim3(512), 0, stream>>>(
      xb, wqkv, (void*)qkv, 8192, 3072, 2048);

  // K rearrange + fused K-rope ; V rearrange (no rope)
  krearr<<<dim3(2048), dim3(256), 0, stream>>>(qkv, K2, rope);
  vrearr2<<<dim3(256), dim3(256), 0, stream>>>(qkv, V2);

  // attention with fused Q-rope
  attn_kernel<<<dim3(T_ / 256, NH, B_), dim3(512), 0, stream>>>(qkv, K2, V2, yb, rope);

  gemm256<0><<<dim3(2048 / 256, 8192 / 256), dim3(512), 0, stream>>>(
      yb, wob, (void*)out, 8192, 2048, 2048);
}